// Round 2
// baseline (1972.967 us; speedup 1.0000x reference)
//
#include <hip/hip_runtime.h>
#include <math.h>

#define BATCH 4
#define SEQ   4096
#define DM    128
#define TOPK  64

// ---------- RoPE prep: rq/rk = rope(q/k) ----------
__global__ void rope_prep(const float* __restrict__ q, const float* __restrict__ k,
                          float* __restrict__ rq, float* __restrict__ rk) {
    int idx = blockIdx.x * blockDim.x + threadIdx.x;
    const int total = BATCH * SEQ * (DM / 2);
    if (idx >= total) return;
    int i   = idx & 63;                 // pair index 0..63
    int pos = (idx >> 6) & (SEQ - 1);
    int b   = idx >> 18;                // / (64*4096)
    float ex  = (float)(2 * i) / (float)DM;
    float dv  = powf(10000.0f, ex);
    float ang = (float)pos / dv;
    float sn, cs;
    sincosf(ang, &sn, &cs);
    size_t base = ((size_t)b * SEQ + pos) * DM + 2 * i;
    float qe = q[base], qo = q[base + 1];
    float ke = k[base], ko = k[base + 1];
    rq[base]     = qe * cs - qo * sn;
    rq[base + 1] = qe * sn + qo * cs;
    rk[base]     = ke * cs - ko * sn;
    rk[base + 1] = ke * sn + ko * cs;
}

// monotonic float->uint mapping (order-preserving, handles negatives)
__device__ __forceinline__ unsigned fmap(float f) {
    unsigned u = __float_as_uint(f);
    return (u & 0x80000000u) ? ~u : (u | 0x80000000u);
}
__device__ __forceinline__ float finv(unsigned u) {
    return (u & 0x80000000u) ? __uint_as_float(u & 0x7FFFFFFFu) : __uint_as_float(~u);
}

// ---------- main: one block per (b, t) row ----------
__launch_bounds__(256)
__global__ void topk_attn(const float* __restrict__ rq, const float* __restrict__ rk,
                          const float* __restrict__ v, float* __restrict__ out) {
    __shared__ unsigned umap[SEQ];      // 16 KB mapped logits
    __shared__ float    qs[DM];
    __shared__ int      selIdx[TOPK];
    __shared__ float    selW[TOPK];
    __shared__ int      cnt;
    __shared__ float    redf[4];
    __shared__ int      redi[4];
    __shared__ float    sMax, sSum;

    const int t   = blockIdx.x & (SEQ - 1);
    const int b   = blockIdx.x >> 12;
    const int tid = threadIdx.x;
    const int lane = tid & 63, wid = tid >> 6;
    const int n = t + 1;
    const float scale = 0.08838834764831845f;   // 1/sqrt(128)

    if (tid < DM) qs[tid] = rq[((size_t)b * SEQ + t) * DM + tid];
    if (tid == 0) cnt = 0;
    __syncthreads();

    // ---- logits for s = 0..t ----
    float lmax = -INFINITY;
    for (int s = tid; s < n; s += 256) {
        const float4* kr = (const float4*)(rk + ((size_t)b * SEQ + s) * DM);
        const float4* qr = (const float4*)qs;
        float acc = 0.f;
        #pragma unroll
        for (int d = 0; d < DM / 4; ++d) {
            float4 kv = kr[d];
            float4 qv = qr[d];
            acc += kv.x * qv.x + kv.y * qv.y + kv.z * qv.z + kv.w * qv.w;
        }
        float lg = acc * scale;
        umap[s] = fmap(lg);
        lmax = fmaxf(lmax, lg);
    }
    // block max
    #pragma unroll
    for (int off = 32; off; off >>= 1) lmax = fmaxf(lmax, __shfl_down(lmax, off));
    if (lane == 0) redf[wid] = lmax;
    __syncthreads();
    if (tid == 0) sMax = fmaxf(fmaxf(redf[0], redf[1]), fmaxf(redf[2], redf[3]));
    __syncthreads();
    const float M = sMax;

    // ---- find 64th-largest via binary search on uint mapping ----
    // invariant: count(>= lo) >= K always; count(>= hi+1) < K.
    // 64-bit bracket arithmetic (32-bit (hi-lo+1) overflows and hangs).
    const int K = (n < TOPK) ? n : TOPK;
    unsigned thr = 0u;
    if (n > TOPK) {
        unsigned long long lo = 0ull, hi = (unsigned long long)fmap(M);
        while (lo < hi) {
            unsigned long long mid = (lo + hi + 1ull) >> 1;
            unsigned m32 = (unsigned)mid;
            int c = 0;
            for (int s = tid; s < n; s += 256) c += (umap[s] >= m32) ? 1 : 0;
            #pragma unroll
            for (int off = 32; off; off >>= 1) c += __shfl_down(c, off);
            if (lane == 0) redi[wid] = c;
            __syncthreads();
            int tot = redi[0] + redi[1] + redi[2] + redi[3];
            __syncthreads();
            if (tot >= K) lo = mid; else hi = mid - 1ull;
        }
        thr = (unsigned)lo;
    }

    // ---- gather selected (strictly greater first, then equal, cap 64) ----
    for (int s = tid; s < n; s += 256) {
        if (umap[s] > thr) {
            int p = atomicAdd(&cnt, 1);
            if (p < TOPK) { selIdx[p] = s; selW[p] = expf(finv(umap[s]) - M); }
        }
    }
    __syncthreads();
    for (int s = tid; s < n; s += 256) {
        if (umap[s] == thr) {
            int p = atomicAdd(&cnt, 1);
            if (p < TOPK) { selIdx[p] = s; selW[p] = expf(finv(umap[s]) - M); }
        }
    }
    __syncthreads();
    const int nsel = (cnt < TOPK) ? cnt : TOPK;

    // ---- softmax denom ----
    if (tid < 64) {
        float w = (tid < nsel) ? selW[tid] : 0.f;
        #pragma unroll
        for (int off = 32; off; off >>= 1) w += __shfl_down(w, off);
        if (tid == 0) sSum = w;
    }
    __syncthreads();
    const float inv = 1.0f / sSum;

    // ---- weighted V gather: threads 0..127 each own one dim ----
    if (tid < DM) {
        float acc = 0.f;
        for (int j = 0; j < nsel; ++j) {
            acc += selW[j] * v[((size_t)b * SEQ + selIdx[j]) * DM + tid];
        }
        out[((size_t)b * SEQ + t) * DM + tid] = acc * inv;
    }
}

extern "C" void kernel_launch(void* const* d_in, const int* in_sizes, int n_in,
                              void* d_out, int out_size, void* d_ws, size_t ws_size,
                              hipStream_t stream) {
    const float* q = (const float*)d_in[0];
    const float* k = (const float*)d_in[1];
    const float* v = (const float*)d_in[2];
    float* out = (float*)d_out;

    float* rq = (float*)d_ws;                       // 8 MB
    float* rk = rq + (size_t)BATCH * SEQ * DM;      // 8 MB

    const int total = BATCH * SEQ * (DM / 2);
    hipLaunchKernelGGL(rope_prep, dim3((total + 255) / 256), dim3(256), 0, stream,
                       q, k, rq, rk);
    hipLaunchKernelGGL(topk_attn, dim3(BATCH * SEQ), dim3(256), 0, stream,
                       rq, rk, v, out);
}

// Round 3
// 494.802 us; speedup vs baseline: 3.9874x; 3.9874x over previous
//
#include <hip/hip_runtime.h>
#include <math.h>

#define BATCH 4
#define SEQ   4096
#define DM    128
#define TOPK  64
#define SCALE 0.08838834764831845f   // 1/sqrt(128)

// ---------- RoPE prep: rq/rk = rope(q/k) ----------
__global__ void rope_prep(const float* __restrict__ q, const float* __restrict__ k,
                          float* __restrict__ rq, float* __restrict__ rk) {
    int idx = blockIdx.x * blockDim.x + threadIdx.x;
    const int total = BATCH * SEQ * (DM / 2);
    if (idx >= total) return;
    int i   = idx & 63;
    int pos = (idx >> 6) & (SEQ - 1);
    int b   = idx >> 18;
    float ex  = (float)(2 * i) / (float)DM;
    float dv  = powf(10000.0f, ex);
    float ang = (float)pos / dv;
    float sn, cs;
    sincosf(ang, &sn, &cs);
    size_t base = ((size_t)b * SEQ + pos) * DM + 2 * i;
    float qe = q[base], qo = q[base + 1];
    float ke = k[base], ko = k[base + 1];
    rq[base]     = qe * cs - qo * sn;
    rq[base + 1] = qe * sn + qo * cs;
    rk[base]     = ke * cs - ko * sn;
    rk[base + 1] = ke * sn + ko * cs;
}

__device__ __forceinline__ unsigned fmap(float f) {
    unsigned u = __float_as_uint(f);
    return (u & 0x80000000u) ? ~u : (u | 0x80000000u);
}
__device__ __forceinline__ float finv(unsigned u) {
    return (u & 0x80000000u) ? __uint_as_float(u & 0x7FFFFFFFu) : __uint_as_float(~u);
}

// ---------- Phase A: logits GEMM (64x64 tiles, fp32, scaled) ----------
// lg layout: [B][m][stride], row (b, t) at ((b*m + t-r0) * stride), valid s <= t.
__launch_bounds__(256, 2)
__global__ void logits_gemm(const float* __restrict__ rq, const float* __restrict__ rk,
                            float* __restrict__ lg, int r0, int m, int stride) {
    const int st = blockIdx.x, qt = blockIdx.y, b = blockIdx.z;
    const int Q0 = r0 + qt * 64, S0 = st * 64;
    if (S0 > Q0 + 63) return;          // strictly above causal diagonal

    __shared__ float4 qs4[64 * 32];    // (r, g) at r*32 + (g ^ (r&31))
    __shared__ float4 ks4[64 * 32];
    const int tid = threadIdx.x;

    for (int f = tid; f < 64 * 32; f += 256) {
        int r = f >> 5, g = f & 31;
        float4 qv = ((const float4*)rq)[((size_t)b * SEQ + Q0 + r) * 32 + g];
        qv.x *= SCALE; qv.y *= SCALE; qv.z *= SCALE; qv.w *= SCALE;
        qs4[(r << 5) + (g ^ (r & 31))] = qv;
        ks4[(r << 5) + (g ^ (r & 31))] =
            ((const float4*)rk)[((size_t)b * SEQ + S0 + r) * 32 + g];
    }
    __syncthreads();

    const int tx = tid & 15, ty = tid >> 4;
    float acc[4][4] = {};
    #pragma unroll 4
    for (int g = 0; g < 32; ++g) {
        float4 a4[4], b4[4];
        #pragma unroll
        for (int i = 0; i < 4; ++i) { int r = ty + 16 * i; a4[i] = qs4[(r << 5) + (g ^ (r & 31))]; }
        #pragma unroll
        for (int j = 0; j < 4; ++j) { int r = tx + 16 * j; b4[j] = ks4[(r << 5) + (g ^ (r & 31))]; }
        #pragma unroll
        for (int i = 0; i < 4; ++i)
            #pragma unroll
            for (int j = 0; j < 4; ++j)
                acc[i][j] += a4[i].x * b4[j].x + a4[i].y * b4[j].y +
                             a4[i].z * b4[j].z + a4[i].w * b4[j].w;
    }

    #pragma unroll
    for (int i = 0; i < 4; ++i) {
        int t = Q0 + ty + 16 * i;
        size_t base = ((size_t)(b * m + (t - r0))) * stride;
        #pragma unroll
        for (int j = 0; j < 4; ++j) {
            int s = S0 + tx + 16 * j;
            if (s <= t) lg[base + s] = acc[i][j];
        }
    }
}

// ---------- Phase B: histogram select + softmax + V gather ----------
__launch_bounds__(256)
__global__ void select_out(const float* __restrict__ lg, const float* __restrict__ v,
                           float* __restrict__ out, int r0, int m, int stride) {
    const int x = blockIdx.x, b = blockIdx.y;
    const int t = r0 + x, n = t + 1, tid = threadIdx.x;
    const int lane = tid & 63, wid = tid >> 6;
    const float* row = lg + ((size_t)(b * m + x)) * stride;

    __shared__ int   hist[4096];
    __shared__ int   ssum[256];
    __shared__ float bufV[320];
    __shared__ int   bufI[320];
    __shared__ float selW[TOPK];
    __shared__ int   selIdx[TOPK];
    __shared__ int   cnt, binB;
    __shared__ float redf[4];
    __shared__ float sM, sS;

    if (n <= TOPK) {                      // trivial rows: all selected
        float val = (tid < n) ? row[tid] : -INFINITY;
        float mx = val;
        #pragma unroll
        for (int off = 32; off; off >>= 1) mx = fmaxf(mx, __shfl_down(mx, off));
        if (lane == 0) redf[wid] = mx;
        __syncthreads();
        if (tid == 0) sM = fmaxf(fmaxf(redf[0], redf[1]), fmaxf(redf[2], redf[3]));
        __syncthreads();
        float w = (tid < n) ? expf(val - sM) : 0.f;
        if (tid < TOPK) { selW[tid] = w; selIdx[tid] = tid; }
        float sm = w;
        #pragma unroll
        for (int off = 32; off; off >>= 1) sm += __shfl_down(sm, off);
        if (lane == 0) redf[wid] = sm;
        __syncthreads();
        if (tid == 0) sS = redf[0] + redf[1] + redf[2] + redf[3];
        __syncthreads();
        float inv = 1.f / sS;
        if (tid < DM) {
            float a = 0.f;
            for (int j = 0; j < n; ++j)
                a += selW[j] * v[((size_t)b * SEQ + selIdx[j]) * DM + tid];
            out[((size_t)b * SEQ + t) * DM + tid] = a * inv;
        }
        return;
    }

    if (tid == 0) cnt = 0;
    for (int i = tid; i < 4096; i += 256) hist[i] = 0;
    __syncthreads();

    // pass 1: 4096-bin histogram on top 12 bits of order-preserving uint
    for (int s = tid; s < n; s += 256)
        atomicAdd(&hist[fmap(row[s]) >> 20], 1);
    __syncthreads();

    // segment sums (256 segs x 16 bins) then suffix-sum S[j] = sum_{j' >= j}
    int ssv = 0;
    #pragma unroll
    for (int k2 = 0; k2 < 16; ++k2) ssv += hist[tid * 16 + k2];
    ssum[tid] = ssv;
    __syncthreads();
    for (int off = 1; off < 256; off <<= 1) {
        int add = (tid + off < 256) ? ssum[tid + off] : 0;
        __syncthreads();
        ssum[tid] += add;
        __syncthreads();
    }
    if (tid == 0) {
        int j = 255;
        while (ssum[j] < TOPK) --j;              // ssum[0] = n > 64, terminates
        int C = (j < 255) ? ssum[j + 1] : 0;
        int w2 = 15, bi;
        for (;; --w2) { bi = j * 16 + w2; C += hist[bi]; if (C >= TOPK) break; }
        binB = bi;
    }
    __syncthreads();
    const unsigned thrU = ((unsigned)binB) << 20;

    // pass 2: gather candidates (everything in bins >= binB)
    for (int s = tid; s < n; s += 256) {
        float val = row[s];
        if (fmap(val) >= thrU) {
            int p = atomicAdd(&cnt, 1);
            if (p < 320) { bufV[p] = val; bufI[p] = s; }
        }
    }
    __syncthreads();
    int C = cnt; if (C > 320) C = 320;

    // row max over candidates
    float mx = -INFINITY;
    for (int c = tid; c < C; c += 256) mx = fmaxf(mx, bufV[c]);
    #pragma unroll
    for (int off = 32; off; off >>= 1) mx = fmaxf(mx, __shfl_down(mx, off));
    if (lane == 0) redf[wid] = mx;
    __syncthreads();
    if (tid == 0) sM = fmaxf(fmaxf(redf[0], redf[1]), fmaxf(redf[2], redf[3]));
    __syncthreads();
    const float M = sM;

    // exact rank (ties by original index asc -> deterministic, matches top_k)
    for (int c = tid; c < C; c += 256) {
        float vc = bufV[c]; int ic = bufI[c];
        int r = 0;
        for (int j2 = 0; j2 < C; ++j2) {
            float vj = bufV[j2];
            r += (vj > vc) || (vj == vc && bufI[j2] < ic);
        }
        if (r < TOPK) { selW[r] = expf(vc - M); selIdx[r] = ic; }
    }
    __syncthreads();

    float w = (tid < TOPK) ? selW[tid] : 0.f;
    #pragma unroll
    for (int off = 32; off; off >>= 1) w += __shfl_down(w, off);
    if (lane == 0) redf[wid] = w;
    __syncthreads();
    if (tid == 0) sS = redf[0] + redf[1] + redf[2] + redf[3];
    __syncthreads();
    const float inv = 1.f / sS;

    if (tid < DM) {
        float a = 0.f;
        for (int j2 = 0; j2 < TOPK; ++j2)
            a += selW[j2] * v[((size_t)b * SEQ + selIdx[j2]) * DM + tid];
        out[((size_t)b * SEQ + t) * DM + tid] = a * inv;
    }
}

// ---------- fallback (round-2 working kernel) ----------
__launch_bounds__(256)
__global__ void topk_attn(const float* __restrict__ rq, const float* __restrict__ rk,
                          const float* __restrict__ v, float* __restrict__ out) {
    __shared__ unsigned umap[SEQ];
    __shared__ float    qs[DM];
    __shared__ int      selIdx[TOPK];
    __shared__ float    selW[TOPK];
    __shared__ int      cnt;
    __shared__ float    redf[4];
    __shared__ int      redi[4];
    __shared__ float    sMax, sSum;

    const int t   = blockIdx.x & (SEQ - 1);
    const int b   = blockIdx.x >> 12;
    const int tid = threadIdx.x;
    const int lane = tid & 63, wid = tid >> 6;
    const int n = t + 1;

    if (tid < DM) qs[tid] = rq[((size_t)b * SEQ + t) * DM + tid];
    if (tid == 0) cnt = 0;
    __syncthreads();

    float lmax = -INFINITY;
    for (int s = tid; s < n; s += 256) {
        const float4* kr = (const float4*)(rk + ((size_t)b * SEQ + s) * DM);
        const float4* qr = (const float4*)qs;
        float acc = 0.f;
        #pragma unroll
        for (int d = 0; d < DM / 4; ++d) {
            float4 kv = kr[d]; float4 qv = qr[d];
            acc += kv.x * qv.x + kv.y * qv.y + kv.z * qv.z + kv.w * qv.w;
        }
        float lgv = acc * SCALE;
        umap[s] = fmap(lgv);
        lmax = fmaxf(lmax, lgv);
    }
    #pragma unroll
    for (int off = 32; off; off >>= 1) lmax = fmaxf(lmax, __shfl_down(lmax, off));
    if (lane == 0) redf[wid] = lmax;
    __syncthreads();
    if (tid == 0) sMax = fmaxf(fmaxf(redf[0], redf[1]), fmaxf(redf[2], redf[3]));
    __syncthreads();
    const float M = sMax;

    const int K = (n < TOPK) ? n : TOPK;
    unsigned thr = 0u;
    if (n > TOPK) {
        unsigned long long lo = 0ull, hi = (unsigned long long)fmap(M);
        while (lo < hi) {
            unsigned long long mid = (lo + hi + 1ull) >> 1;
            unsigned m32 = (unsigned)mid;
            int c = 0;
            for (int s = tid; s < n; s += 256) c += (umap[s] >= m32) ? 1 : 0;
            #pragma unroll
            for (int off = 32; off; off >>= 1) c += __shfl_down(c, off);
            if (lane == 0) redi[wid] = c;
            __syncthreads();
            int tot = redi[0] + redi[1] + redi[2] + redi[3];
            __syncthreads();
            if (tot >= K) lo = mid; else hi = mid - 1ull;
        }
        thr = (unsigned)lo;
    }

    for (int s = tid; s < n; s += 256) {
        if (umap[s] > thr) {
            int p = atomicAdd(&cnt, 1);
            if (p < TOPK) { selIdx[p] = s; selW[p] = expf(finv(umap[s]) - M); }
        }
    }
    __syncthreads();
    for (int s = tid; s < n; s += 256) {
        if (umap[s] == thr) {
            int p = atomicAdd(&cnt, 1);
            if (p < TOPK) { selIdx[p] = s; selW[p] = expf(finv(umap[s]) - M); }
        }
    }
    __syncthreads();
    const int nsel = (cnt < TOPK) ? cnt : TOPK;

    if (tid < 64) {
        float w = (tid < nsel) ? selW[tid] : 0.f;
        #pragma unroll
        for (int off = 32; off; off >>= 1) w += __shfl_down(w, off);
        if (tid == 0) sSum = w;
    }
    __syncthreads();
    const float inv = 1.0f / sSum;

    if (tid < DM) {
        float a = 0.f;
        for (int j = 0; j < nsel; ++j)
            a += selW[j] * v[((size_t)b * SEQ + selIdx[j]) * DM + tid];
        out[((size_t)b * SEQ + t) * DM + tid] = a * inv;
    }
}

extern "C" void kernel_launch(void* const* d_in, const int* in_sizes, int n_in,
                              void* d_out, int out_size, void* d_ws, size_t ws_size,
                              hipStream_t stream) {
    const float* q = (const float*)d_in[0];
    const float* k = (const float*)d_in[1];
    const float* v = (const float*)d_in[2];
    float* out = (float*)d_out;

    float* rq = (float*)d_ws;
    float* rk = rq + (size_t)BATCH * SEQ * DM;
    const size_t ropeBytes = 2ull * BATCH * SEQ * DM * sizeof(float);

    const int total = BATCH * SEQ * (DM / 2);
    hipLaunchKernelGGL(rope_prep, dim3((total + 255) / 256), dim3(256), 0, stream,
                       q, k, rq, rk);

    // plan query-row chunks so [B][m][stride] fp32 logits fit in remaining ws
    long long Wb = (long long)ws_size - (long long)ropeBytes;
    int cr0[64], cm[64], nch = 0;
    bool ok = (Wb > 0);
    int r0 = 0;
    while (ok && r0 < SEQ) {
        int m = SEQ - r0;
        while (m >= 64) {
            long long bytes = (long long)BATCH * m * (((r0 + m + 63) / 64) * 64) * 4;
            if (bytes <= Wb) break;
            m -= 64;
        }
        if (m < 64 || nch >= 64) { ok = false; break; }
        cr0[nch] = r0; cm[nch] = m; ++nch;
        r0 += m;
    }

    if (!ok) {   // workspace too small: round-2 kernel (known-good, needs only rope)
        hipLaunchKernelGGL(topk_attn, dim3(BATCH * SEQ), dim3(256), 0, stream,
                           rq, rk, v, out);
        return;
    }

    float* lgbuf = rk + (size_t)BATCH * SEQ * DM;
    for (int c = 0; c < nch; ++c) {
        const int R0 = cr0[c], M = cm[c];
        const int stride = ((R0 + M + 63) / 64) * 64;
        dim3 g1((R0 + M + 63) / 64, M / 64, BATCH);
        hipLaunchKernelGGL(logits_gemm, g1, dim3(256), 0, stream,
                           rq, rk, lgbuf, R0, M, stride);
        dim3 g2(M, BATCH);
        hipLaunchKernelGGL(select_out, g2, dim3(256), 0, stream,
                           lgbuf, v, out, R0, M, stride);
    }
}

// Round 4
// 450.853 us; speedup vs baseline: 4.3761x; 1.0975x over previous
//
#include <hip/hip_runtime.h>
#include <math.h>

#define BATCH 4
#define SEQ   4096
#define DM    128
#define TOPK  64
#define SCALE 0.08838834764831845f   // 1/sqrt(128)
#define NBIN  2048                   // 11-bit histogram
#define CANDMAX 512

// ---------- RoPE prep: rq/rk = rope(q/k) ----------
__global__ void rope_prep(const float* __restrict__ q, const float* __restrict__ k,
                          float* __restrict__ rq, float* __restrict__ rk) {
    int idx = blockIdx.x * blockDim.x + threadIdx.x;
    const int total = BATCH * SEQ * (DM / 2);
    if (idx >= total) return;
    int i   = idx & 63;
    int pos = (idx >> 6) & (SEQ - 1);
    int b   = idx >> 18;
    float ex  = (float)(2 * i) / (float)DM;
    float dv  = powf(10000.0f, ex);
    float ang = (float)pos / dv;
    float sn, cs;
    sincosf(ang, &sn, &cs);
    size_t base = ((size_t)b * SEQ + pos) * DM + 2 * i;
    float qe = q[base], qo = q[base + 1];
    float ke = k[base], ko = k[base + 1];
    rq[base]     = qe * cs - qo * sn;
    rq[base + 1] = qe * sn + qo * cs;
    rk[base]     = ke * cs - ko * sn;
    rk[base + 1] = ke * sn + ko * cs;
}

__device__ __forceinline__ unsigned fmap(float f) {
    unsigned u = __float_as_uint(f);
    return (u & 0x80000000u) ? ~u : (u | 0x80000000u);
}
__device__ __forceinline__ float finv(unsigned u) {
    return (u & 0x80000000u) ? __uint_as_float(u & 0x7FFFFFFFu) : __uint_as_float(~u);
}

// ---------- Phase A: logits GEMM (64x64 tiles, fp32, scaled) ----------
__launch_bounds__(256, 2)
__global__ void logits_gemm(const float* __restrict__ rq, const float* __restrict__ rk,
                            float* __restrict__ lg, int r0, int m, int stride) {
    const int st = blockIdx.x, qt = blockIdx.y, b = blockIdx.z;
    const int Q0 = r0 + qt * 64, S0 = st * 64;
    if (S0 > Q0 + 63) return;

    __shared__ float4 qs4[64 * 32];
    __shared__ float4 ks4[64 * 32];
    const int tid = threadIdx.x;

    for (int f = tid; f < 64 * 32; f += 256) {
        int r = f >> 5, g = f & 31;
        float4 qv = ((const float4*)rq)[((size_t)b * SEQ + Q0 + r) * 32 + g];
        qv.x *= SCALE; qv.y *= SCALE; qv.z *= SCALE; qv.w *= SCALE;
        qs4[(r << 5) + (g ^ (r & 31))] = qv;
        ks4[(r << 5) + (g ^ (r & 31))] =
            ((const float4*)rk)[((size_t)b * SEQ + S0 + r) * 32 + g];
    }
    __syncthreads();

    const int tx = tid & 15, ty = tid >> 4;
    float acc[4][4] = {};
    #pragma unroll 4
    for (int g = 0; g < 32; ++g) {
        float4 a4[4], b4[4];
        #pragma unroll
        for (int i = 0; i < 4; ++i) { int r = ty + 16 * i; a4[i] = qs4[(r << 5) + (g ^ (r & 31))]; }
        #pragma unroll
        for (int j = 0; j < 4; ++j) { int r = tx + 16 * j; b4[j] = ks4[(r << 5) + (g ^ (r & 31))]; }
        #pragma unroll
        for (int i = 0; i < 4; ++i)
            #pragma unroll
            for (int j = 0; j < 4; ++j)
                acc[i][j] += a4[i].x * b4[j].x + a4[i].y * b4[j].y +
                             a4[i].z * b4[j].z + a4[i].w * b4[j].w;
    }

    #pragma unroll
    for (int i = 0; i < 4; ++i) {
        int t = Q0 + ty + 16 * i;
        size_t base = ((size_t)(b * m + (t - r0))) * stride;
        #pragma unroll
        for (int j = 0; j < 4; ++j) {
            int s = S0 + tx + 16 * j;
            if (s <= t) lg[base + s] = acc[i][j];
        }
    }
}

// ---------- Phase B: histogram select + softmax + V gather ----------
__launch_bounds__(256)
__global__ void select_out(const float* __restrict__ lg, const float* __restrict__ v,
                           float* __restrict__ out, int r0, int m, int stride) {
    const int x = blockIdx.x, b = blockIdx.y;
    const int t = r0 + x, n = t + 1, tid = threadIdx.x;
    const int lane = tid & 63, wid = tid >> 6;
    const float* row = lg + ((size_t)(b * m + x)) * stride;

    __shared__ unsigned umapS[SEQ];       // 16 KB
    __shared__ int      hist[NBIN];       // 8 KB
    __shared__ int      sfx[256];         // 1 KB
    __shared__ unsigned bufU[CANDMAX];    // 2 KB
    __shared__ int      bufI[CANDMAX];    // 2 KB
    __shared__ float    selW[TOPK];
    __shared__ int      selIdx[TOPK];
    __shared__ int      cnt, jBs, binBs;
    __shared__ unsigned redu[4];
    __shared__ float    redf[4];
    __shared__ float    sM, sS;

    if (n <= TOPK) {                      // trivial rows: all selected
        float val = (tid < n) ? row[tid] : -INFINITY;
        float mx = val;
        #pragma unroll
        for (int off = 32; off; off >>= 1) mx = fmaxf(mx, __shfl_down(mx, off));
        if (lane == 0) redf[wid] = mx;
        __syncthreads();
        if (tid == 0) sM = fmaxf(fmaxf(redf[0], redf[1]), fmaxf(redf[2], redf[3]));
        __syncthreads();
        float w = (tid < n) ? expf(val - sM) : 0.f;
        if (tid < TOPK) { selW[tid] = w; selIdx[tid] = tid; }
        float sm = w;
        #pragma unroll
        for (int off = 32; off; off >>= 1) sm += __shfl_down(sm, off);
        if (lane == 0) redf[wid] = sm;
        __syncthreads();
        if (tid == 0) sS = redf[0] + redf[1] + redf[2] + redf[3];
        __syncthreads();
        float inv = 1.f / sS;
        if (tid < DM) {
            float a = 0.f;
            for (int j = 0; j < n; ++j)
                a += selW[j] * v[((size_t)b * SEQ + selIdx[j]) * DM + tid];
            out[((size_t)b * SEQ + t) * DM + tid] = a * inv;
        }
        return;
    }

    if (tid == 0) cnt = 0;
    for (int i = tid; i < NBIN; i += 256) hist[i] = 0;
    __syncthreads();

    // ---- pass 1: float4 reads, LDS umap cache, histogram, uint row-max ----
    const int nv = n & ~3;
    unsigned umax = 0u;
    const float4* row4 = (const float4*)row;
    for (int s4 = (tid << 2); s4 < nv; s4 += 1024) {
        float4 r4 = row4[s4 >> 2];
        unsigned u0 = fmap(r4.x), u1 = fmap(r4.y), u2 = fmap(r4.z), u3 = fmap(r4.w);
        umapS[s4]     = u0; umapS[s4 + 1] = u1;
        umapS[s4 + 2] = u2; umapS[s4 + 3] = u3;
        atomicAdd(&hist[u0 >> 21], 1); atomicAdd(&hist[u1 >> 21], 1);
        atomicAdd(&hist[u2 >> 21], 1); atomicAdd(&hist[u3 >> 21], 1);
        unsigned m01 = (u0 > u1) ? u0 : u1, m23 = (u2 > u3) ? u2 : u3;
        unsigned m03 = (m01 > m23) ? m01 : m23;
        if (m03 > umax) umax = m03;
    }
    if (tid < n - nv) {                    // tail (<=3 elems)
        unsigned u = fmap(row[nv + tid]);
        umapS[nv + tid] = u;
        atomicAdd(&hist[u >> 21], 1);
        if (u > umax) umax = u;
    }
    // block max (uint)
    #pragma unroll
    for (int off = 32; off; off >>= 1) {
        unsigned o = __shfl_down(umax, off);
        if (o > umax) umax = o;
    }
    if (lane == 0) redu[wid] = umax;
    __syncthreads();
    if (tid == 0) {
        unsigned a0 = redu[0] > redu[1] ? redu[0] : redu[1];
        unsigned a1 = redu[2] > redu[3] ? redu[2] : redu[3];
        sM = finv(a0 > a1 ? a0 : a1);
    }

    // ---- segment sums + suffix scan (8 bins / segment) ----
    int seg = 0;
    #pragma unroll
    for (int k2 = 0; k2 < 8; ++k2) seg += hist[tid * 8 + k2];
    sfx[tid] = seg;
    __syncthreads();
    #pragma unroll
    for (int off = 1; off < 256; off <<= 1) {
        int add = (tid + off < 256) ? sfx[tid + off] : 0;
        __syncthreads();
        sfx[tid] += add;
        __syncthreads();
    }

    // ---- parallel boundary-segment find, short serial bin walk ----
    const int K = TOPK;                    // n > TOPK here
    if (sfx[tid] >= K && (tid == 255 || sfx[tid + 1] < K)) jBs = tid;
    __syncthreads();
    if (tid == 0) {
        int j = jBs, base = j * 8;
        int Cacc = (j < 255) ? sfx[j + 1] : 0;
        int bi = base;
        #pragma unroll
        for (int w2 = 7; w2 >= 0; --w2) {
            Cacc += hist[base + w2];
            if (Cacc >= K) { bi = base + w2; break; }
        }
        binBs = bi;
    }
    __syncthreads();
    const unsigned thrU = ((unsigned)binBs) << 21;
    const float M = sM;

    // ---- pass 2: gather candidates from LDS umap ----
    for (int s = tid; s < n; s += 256) {
        unsigned u = umapS[s];
        if (u >= thrU) {
            int p = atomicAdd(&cnt, 1);
            if (p < CANDMAX) { bufU[p] = u; bufI[p] = s; }
        }
    }
    __syncthreads();
    int C = cnt; if (C > CANDMAX) C = CANDMAX;

    // ---- exact rank on (uint value desc, index asc) ----
    for (int c = tid; c < C; c += 256) {
        unsigned uc = bufU[c]; int ic = bufI[c];
        int r = 0;
        for (int j2 = 0; j2 < C; ++j2) {
            unsigned uj = bufU[j2];
            r += (uj > uc) || (uj == uc && bufI[j2] < ic);
        }
        if (r < TOPK) { selW[r] = expf(finv(uc) - M); selIdx[r] = ic; }
    }
    __syncthreads();

    // ---- softmax denom (TOPK == one wave) ----
    if (tid < 64) {
        float w = selW[tid];
        #pragma unroll
        for (int off = 32; off; off >>= 1) w += __shfl_down(w, off);
        if (tid == 0) sS = w;
    }
    __syncthreads();
    const float inv = 1.f / sS;

    // ---- weighted V gather ----
    if (tid < DM) {
        float a = 0.f;
        #pragma unroll 4
        for (int j2 = 0; j2 < TOPK; ++j2)
            a += selW[j2] * v[((size_t)b * SEQ + selIdx[j2]) * DM + tid];
        out[((size_t)b * SEQ + t) * DM + tid] = a * inv;
    }
}

// ---------- fallback (round-2 working kernel, small-ws path) ----------
__launch_bounds__(256)
__global__ void topk_attn(const float* __restrict__ rq, const float* __restrict__ rk,
                          const float* __restrict__ v, float* __restrict__ out) {
    __shared__ unsigned umap[SEQ];
    __shared__ float    qs[DM];
    __shared__ int      selIdx[TOPK];
    __shared__ float    selW[TOPK];
    __shared__ int      cnt;
    __shared__ float    redf[4];
    __shared__ int      redi[4];
    __shared__ float    sMax, sSum;

    const int t   = blockIdx.x & (SEQ - 1);
    const int b   = blockIdx.x >> 12;
    const int tid = threadIdx.x;
    const int lane = tid & 63, wid = tid >> 6;
    const int n = t + 1;

    if (tid < DM) qs[tid] = rq[((size_t)b * SEQ + t) * DM + tid];
    if (tid == 0) cnt = 0;
    __syncthreads();

    float lmax = -INFINITY;
    for (int s = tid; s < n; s += 256) {
        const float4* kr = (const float4*)(rk + ((size_t)b * SEQ + s) * DM);
        const float4* qr = (const float4*)qs;
        float acc = 0.f;
        #pragma unroll
        for (int d = 0; d < DM / 4; ++d) {
            float4 kv = kr[d]; float4 qv = qr[d];
            acc += kv.x * qv.x + kv.y * qv.y + kv.z * qv.z + kv.w * qv.w;
        }
        float lgv = acc * SCALE;
        umap[s] = fmap(lgv);
        lmax = fmaxf(lmax, lgv);
    }
    #pragma unroll
    for (int off = 32; off; off >>= 1) lmax = fmaxf(lmax, __shfl_down(lmax, off));
    if (lane == 0) redf[wid] = lmax;
    __syncthreads();
    if (tid == 0) sMax = fmaxf(fmaxf(redf[0], redf[1]), fmaxf(redf[2], redf[3]));
    __syncthreads();
    const float M = sMax;

    const int K = (n < TOPK) ? n : TOPK;
    unsigned thr = 0u;
    if (n > TOPK) {
        unsigned long long lo = 0ull, hi = (unsigned long long)fmap(M);
        while (lo < hi) {
            unsigned long long mid = (lo + hi + 1ull) >> 1;
            unsigned m32 = (unsigned)mid;
            int c = 0;
            for (int s = tid; s < n; s += 256) c += (umap[s] >= m32) ? 1 : 0;
            #pragma unroll
            for (int off = 32; off; off >>= 1) c += __shfl_down(c, off);
            if (lane == 0) redi[wid] = c;
            __syncthreads();
            int tot = redi[0] + redi[1] + redi[2] + redi[3];
            __syncthreads();
            if (tot >= K) lo = mid; else hi = mid - 1ull;
        }
        thr = (unsigned)lo;
    }

    for (int s = tid; s < n; s += 256) {
        if (umap[s] > thr) {
            int p = atomicAdd(&cnt, 1);
            if (p < TOPK) { selIdx[p] = s; selW[p] = expf(finv(umap[s]) - M); }
        }
    }
    __syncthreads();
    for (int s = tid; s < n; s += 256) {
        if (umap[s] == thr) {
            int p = atomicAdd(&cnt, 1);
            if (p < TOPK) { selIdx[p] = s; selW[p] = expf(finv(umap[s]) - M); }
        }
    }
    __syncthreads();
    const int nsel = (cnt < TOPK) ? cnt : TOPK;

    if (tid < 64) {
        float w = (tid < nsel) ? selW[tid] : 0.f;
        #pragma unroll
        for (int off = 32; off; off >>= 1) w += __shfl_down(w, off);
        if (tid == 0) sSum = w;
    }
    __syncthreads();
    const float inv = 1.0f / sSum;

    if (tid < DM) {
        float a = 0.f;
        for (int j = 0; j < nsel; ++j)
            a += selW[j] * v[((size_t)b * SEQ + selIdx[j]) * DM + tid];
        out[((size_t)b * SEQ + t) * DM + tid] = a * inv;
    }
}

extern "C" void kernel_launch(void* const* d_in, const int* in_sizes, int n_in,
                              void* d_out, int out_size, void* d_ws, size_t ws_size,
                              hipStream_t stream) {
    const float* q = (const float*)d_in[0];
    const float* k = (const float*)d_in[1];
    const float* v = (const float*)d_in[2];
    float* out = (float*)d_out;

    float* rq = (float*)d_ws;
    float* rk = rq + (size_t)BATCH * SEQ * DM;
    const size_t ropeBytes = 2ull * BATCH * SEQ * DM * sizeof(float);

    const int total = BATCH * SEQ * (DM / 2);
    hipLaunchKernelGGL(rope_prep, dim3((total + 255) / 256), dim3(256), 0, stream,
                       q, k, rq, rk);

    long long Wb = (long long)ws_size - (long long)ropeBytes;
    int cr0[64], cm[64], nch = 0;
    bool ok = (Wb > 0);
    int r0 = 0;
    while (ok && r0 < SEQ) {
        int m = SEQ - r0;
        while (m >= 64) {
            long long bytes = (long long)BATCH * m * (((r0 + m + 63) / 64) * 64) * 4;
            if (bytes <= Wb) break;
            m -= 64;
        }
        if (m < 64 || nch >= 64) { ok = false; break; }
        cr0[nch] = r0; cm[nch] = m; ++nch;
        r0 += m;
    }

    if (!ok) {
        hipLaunchKernelGGL(topk_attn, dim3(BATCH * SEQ), dim3(256), 0, stream,
                           rq, rk, v, out);
        return;
    }

    float* lgbuf = rk + (size_t)BATCH * SEQ * DM;
    for (int c = 0; c < nch; ++c) {
        const int R0 = cr0[c], M = cm[c];
        const int stride = ((R0 + M + 63) / 64) * 64;
        dim3 g1((R0 + M + 63) / 64, M / 64, BATCH);
        hipLaunchKernelGGL(logits_gemm, g1, dim3(256), 0, stream,
                           rq, rk, lgbuf, R0, M, stride);
        dim3 g2(M, BATCH);
        hipLaunchKernelGGL(select_out, g2, dim3(256), 0, stream,
                           lgbuf, v, out, R0, M, stride);
    }
}

// Round 5
// 309.514 us; speedup vs baseline: 6.3744x; 1.4566x over previous
//
#include <hip/hip_runtime.h>
#include <math.h>

#define BATCH 4
#define SEQ   4096
#define DM    128
#define TOPK  64
#define SCALE 0.08838834764831845f   // 1/sqrt(128)
#define CAP   384                    // candidate buffer per row

// ---------- RoPE prep: rq/rk = rope(q/k) ----------
__global__ void rope_prep(const float* __restrict__ q, const float* __restrict__ k,
                          float* __restrict__ rq, float* __restrict__ rk) {
    int idx = blockIdx.x * blockDim.x + threadIdx.x;
    const int total = BATCH * SEQ * (DM / 2);
    if (idx >= total) return;
    int i   = idx & 63;
    int pos = (idx >> 6) & (SEQ - 1);
    int b   = idx >> 18;
    float ex  = (float)(2 * i) / (float)DM;
    float dv  = powf(10000.0f, ex);
    float ang = (float)pos / dv;
    float sn, cs;
    sincosf(ang, &sn, &cs);
    size_t base = ((size_t)b * SEQ + pos) * DM + 2 * i;
    float qe = q[base], qo = q[base + 1];
    float ke = k[base], ko = k[base + 1];
    rq[base]     = qe * cs - qo * sn;
    rq[base + 1] = qe * sn + qo * cs;
    rk[base]     = ke * cs - ko * sn;
    rk[base + 1] = ke * sn + ko * cs;
}

__device__ __forceinline__ unsigned fmap(float f) {
    unsigned u = __float_as_uint(f);
    return (u & 0x80000000u) ? ~u : (u | 0x80000000u);
}
__device__ __forceinline__ float finv(unsigned u) {
    return (u & 0x80000000u) ? __uint_as_float(u & 0x7FFFFFFFu) : __uint_as_float(~u);
}

__device__ __forceinline__ float wave_fmax(float v) {
    #pragma unroll
    for (int m = 32; m; m >>= 1) v = fmaxf(v, __shfl_xor(v, m));
    return v;
}
__device__ __forceinline__ float wave_fsum(float v) {
    #pragma unroll
    for (int m = 32; m; m >>= 1) v += __shfl_xor(v, m);
    return v;
}
__device__ __forceinline__ int wave_isum(int v) {
    #pragma unroll
    for (int m = 32; m; m >>= 1) v += __shfl_xor(v, m);
    return v;
}
__device__ __forceinline__ unsigned wave_umax(unsigned v) {
    #pragma unroll
    for (int m = 32; m; m >>= 1) { unsigned o = __shfl_xor(v, m); v = (o > v) ? o : v; }
    return v;
}

// ---------- Phase A: logits GEMM (64x64 tiles, fp32, scaled) ----------
__launch_bounds__(256, 2)
__global__ void logits_gemm(const float* __restrict__ rq, const float* __restrict__ rk,
                            float* __restrict__ lg, int r0, int m, int stride) {
    const int st = blockIdx.x, qt = blockIdx.y, b = blockIdx.z;
    const int Q0 = r0 + qt * 64, S0 = st * 64;
    if (S0 > Q0 + 63) return;

    __shared__ float4 qs4[64 * 32];
    __shared__ float4 ks4[64 * 32];
    const int tid = threadIdx.x;

    for (int f = tid; f < 64 * 32; f += 256) {
        int r = f >> 5, g = f & 31;
        float4 qv = ((const float4*)rq)[((size_t)b * SEQ + Q0 + r) * 32 + g];
        qv.x *= SCALE; qv.y *= SCALE; qv.z *= SCALE; qv.w *= SCALE;
        qs4[(r << 5) + (g ^ (r & 31))] = qv;
        ks4[(r << 5) + (g ^ (r & 31))] =
            ((const float4*)rk)[((size_t)b * SEQ + S0 + r) * 32 + g];
    }
    __syncthreads();

    const int tx = tid & 15, ty = tid >> 4;
    float acc[4][4] = {};
    #pragma unroll 4
    for (int g = 0; g < 32; ++g) {
        float4 a4[4], b4[4];
        #pragma unroll
        for (int i = 0; i < 4; ++i) { int r = ty + 16 * i; a4[i] = qs4[(r << 5) + (g ^ (r & 31))]; }
        #pragma unroll
        for (int j = 0; j < 4; ++j) { int r = tx + 16 * j; b4[j] = ks4[(r << 5) + (g ^ (r & 31))]; }
        #pragma unroll
        for (int i = 0; i < 4; ++i)
            #pragma unroll
            for (int j = 0; j < 4; ++j)
                acc[i][j] += a4[i].x * b4[j].x + a4[i].y * b4[j].y +
                             a4[i].z * b4[j].z + a4[i].w * b4[j].w;
    }

    #pragma unroll
    for (int i = 0; i < 4; ++i) {
        int t = Q0 + ty + 16 * i;
        size_t base = ((size_t)(b * m + (t - r0))) * stride;
        #pragma unroll
        for (int j = 0; j < 4; ++j) {
            int s = S0 + tx + 16 * j;
            if (s <= t) lg[base + s] = acc[i][j];
        }
    }
}

// ---------- Phase B: one WAVE per row; threshold prefilter + exact rank ----------
__launch_bounds__(256)
__global__ void select_out2(const float* __restrict__ lg, const float* __restrict__ v,
                            float* __restrict__ out, int r0, int m, int stride) {
    __shared__ unsigned long long bufK[4][CAP];   // (fmap(val)<<32) | (SEQ - idx)
    __shared__ float sW[4][TOPK];
    __shared__ int   sI[4][TOPK];
    __shared__ int   cnt[4];

    const int w = threadIdx.x >> 6, lane = threadIdx.x & 63;
    const int x = blockIdx.x * 4 + w, b = blockIdx.y;
    if (x >= m) return;                           // no block barriers anywhere
    const int t = r0 + x, n = t + 1;
    const float* row = lg + ((size_t)(b * m + x)) * stride;
    const float4* row4 = (const float4*)row;
    const int nv4 = n >> 2, rem = n & 3;

    // ---- trivial rows: all n (<=64) positions selected ----
    if (n <= TOPK) {
        float val = (lane < n) ? row[lane] : -3.0e38f;
        float M = wave_fmax(val);
        float wgt = (lane < n) ? expf(val - M) : 0.f;
        float S = wave_fsum(wgt);
        sW[w][lane] = wgt;
        float inv = 1.f / S;
        float a0 = 0.f, a1 = 0.f;
        for (int j = 0; j < n; ++j) {
            float wj = sW[w][j];
            size_t base = ((size_t)b * SEQ + j) * DM;
            a0 += wj * v[base + lane];
            a1 += wj * v[base + 64 + lane];
        }
        size_t ob = ((size_t)b * SEQ + t) * DM;
        out[ob + lane] = a0 * inv;
        out[ob + 64 + lane] = a1 * inv;
        return;
    }

    // ---- initial threshold: Gaussian quantile targeting ~128 candidates ----
    float T;
    if (n <= 300) {
        T = -3.0e38f;                 // take all n (<= 300 <= CAP) candidates
    } else {
        float p  = 128.f / (float)n;  // upper-tail target, p < 0.5
        float tt = sqrtf(-2.f * logf(p));
        T = tt - (2.30753f + 0.27061f * tt) / (1.f + 0.99229f * tt + 0.04481f * tt * tt);
    }

    // ---- count pass(es): adjust T until 64 <= C <= CAP ----
    unsigned um = 0u;
    float Tlo = -3.3e38f, Thi = 3.3e38f;    // Tlo: C>CAP there; Thi: C<K there
    int C = 0;
    for (int it = 0; it < 24; ++it) {
        int c = 0;
        unsigned lm = 0u;
        for (int i = lane; i < nv4; i += 64) {
            float4 r4 = row4[i];
            c += (r4.x >= T) + (r4.y >= T) + (r4.z >= T) + (r4.w >= T);
            if (it == 0) {
                unsigned u0 = fmap(r4.x), u1 = fmap(r4.y), u2 = fmap(r4.z), u3 = fmap(r4.w);
                unsigned a = u0 > u1 ? u0 : u1, bb = u2 > u3 ? u2 : u3;
                a = a > bb ? a : bb;
                lm = a > lm ? a : lm;
            }
        }
        if (lane < rem) {
            float val = row[nv4 * 4 + lane];
            c += (val >= T);
            if (it == 0) { unsigned u = fmap(val); lm = u > lm ? u : lm; }
        }
        C = wave_isum(c);
        if (it == 0) um = wave_umax(lm);
        if (C >= TOPK && C <= CAP) break;
        if (C < TOPK) Thi = T; else Tlo = T;
        if (Tlo > -3.2e38f && Thi < 3.2e38f) T = 0.5f * (Tlo + Thi);
        else if (C < TOPK)                   T = T - 0.45f;
        else                                 T = T + 0.35f;
    }
    const float M = finv(um);

    // ---- append pass: gather candidate keys into LDS ----
    if (lane == 0) cnt[w] = 0;   // same-wave LDS ops are ordered; no barrier needed
    for (int i = lane; i < nv4; i += 64) {
        float4 r4 = row4[i];
        int s = i << 2;
        if (r4.x >= T) { int p = atomicAdd(&cnt[w], 1); if (p < CAP) bufK[w][p] = ((unsigned long long)fmap(r4.x) << 32) | (unsigned)(SEQ - s); }
        if (r4.y >= T) { int p = atomicAdd(&cnt[w], 1); if (p < CAP) bufK[w][p] = ((unsigned long long)fmap(r4.y) << 32) | (unsigned)(SEQ - (s + 1)); }
        if (r4.z >= T) { int p = atomicAdd(&cnt[w], 1); if (p < CAP) bufK[w][p] = ((unsigned long long)fmap(r4.z) << 32) | (unsigned)(SEQ - (s + 2)); }
        if (r4.w >= T) { int p = atomicAdd(&cnt[w], 1); if (p < CAP) bufK[w][p] = ((unsigned long long)fmap(r4.w) << 32) | (unsigned)(SEQ - (s + 3)); }
    }
    if (lane < rem) {
        float val = row[nv4 * 4 + lane];
        if (val >= T) { int p = atomicAdd(&cnt[w], 1); if (p < CAP) bufK[w][p] = ((unsigned long long)fmap(val) << 32) | (unsigned)(SEQ - (nv4 * 4 + lane)); }
    }
    int Cw = cnt[w];
    if (Cw > CAP) Cw = CAP;

    // ---- exact rank: descending key order == (value desc, index asc) ----
    for (int c0 = lane; c0 < Cw; c0 += 64) {
        unsigned long long kc = bufK[w][c0];
        int r = 0;
        for (int j = 0; j < Cw; ++j) r += (bufK[w][j] > kc);
        if (r < TOPK) {
            sW[w][r] = expf(finv((unsigned)(kc >> 32)) - M);
            sI[w][r] = SEQ - (int)(kc & 0xFFFFFFFFu);
        }
    }

    // ---- softmax denom (exactly 64 selected since n > 64) ----
    float S = wave_fsum(sW[w][lane]);
    float inv = 1.f / S;

    // ---- weighted V gather: lane owns dims (lane, lane+64) ----
    float a0 = 0.f, a1 = 0.f;
    #pragma unroll 4
    for (int j = 0; j < TOPK; ++j) {
        float wj = sW[w][j];
        int idx = sI[w][j];
        size_t base = ((size_t)b * SEQ + idx) * DM;
        a0 += wj * v[base + lane];
        a1 += wj * v[base + 64 + lane];
    }
    size_t ob = ((size_t)b * SEQ + t) * DM;
    out[ob + lane] = a0 * inv;
    out[ob + 64 + lane] = a1 * inv;
}

// ---------- fallback (round-2 working kernel, small-ws path) ----------
__launch_bounds__(256)
__global__ void topk_attn(const float* __restrict__ rq, const float* __restrict__ rk,
                          const float* __restrict__ v, float* __restrict__ out) {
    __shared__ unsigned umap[SEQ];
    __shared__ float    qs[DM];
    __shared__ int      selIdx[TOPK];
    __shared__ float    selW[TOPK];
    __shared__ int      cnt;
    __shared__ float    redf[4];
    __shared__ int      redi[4];
    __shared__ float    sMax, sSum;

    const int t   = blockIdx.x & (SEQ - 1);
    const int b   = blockIdx.x >> 12;
    const int tid = threadIdx.x;
    const int lane = tid & 63, wid = tid >> 6;
    const int n = t + 1;

    if (tid < DM) qs[tid] = rq[((size_t)b * SEQ + t) * DM + tid];
    if (tid == 0) cnt = 0;
    __syncthreads();

    float lmax = -INFINITY;
    for (int s = tid; s < n; s += 256) {
        const float4* kr = (const float4*)(rk + ((size_t)b * SEQ + s) * DM);
        const float4* qr = (const float4*)qs;
        float acc = 0.f;
        #pragma unroll
        for (int d = 0; d < DM / 4; ++d) {
            float4 kv = kr[d]; float4 qv = qr[d];
            acc += kv.x * qv.x + kv.y * qv.y + kv.z * qv.z + kv.w * qv.w;
        }
        float lgv = acc * SCALE;
        umap[s] = fmap(lgv);
        lmax = fmaxf(lmax, lgv);
    }
    #pragma unroll
    for (int off = 32; off; off >>= 1) lmax = fmaxf(lmax, __shfl_down(lmax, off));
    if (lane == 0) redf[wid] = lmax;
    __syncthreads();
    if (tid == 0) sMax = fmaxf(fmaxf(redf[0], redf[1]), fmaxf(redf[2], redf[3]));
    __syncthreads();
    const float M = sMax;

    const int K = (n < TOPK) ? n : TOPK;
    unsigned thr = 0u;
    if (n > TOPK) {
        unsigned long long lo = 0ull, hi = (unsigned long long)fmap(M);
        while (lo < hi) {
            unsigned long long mid = (lo + hi + 1ull) >> 1;
            unsigned m32 = (unsigned)mid;
            int c = 0;
            for (int s = tid; s < n; s += 256) c += (umap[s] >= m32) ? 1 : 0;
            #pragma unroll
            for (int off = 32; off; off >>= 1) c += __shfl_down(c, off);
            if (lane == 0) redi[wid] = c;
            __syncthreads();
            int tot = redi[0] + redi[1] + redi[2] + redi[3];
            __syncthreads();
            if (tot >= K) lo = mid; else hi = mid - 1ull;
        }
        thr = (unsigned)lo;
    }

    for (int s = tid; s < n; s += 256) {
        if (umap[s] > thr) {
            int p = atomicAdd(&cnt, 1);
            if (p < TOPK) { selIdx[p] = s; selW[p] = expf(finv(umap[s]) - M); }
        }
    }
    __syncthreads();
    for (int s = tid; s < n; s += 256) {
        if (umap[s] == thr) {
            int p = atomicAdd(&cnt, 1);
            if (p < TOPK) { selIdx[p] = s; selW[p] = expf(finv(umap[s]) - M); }
        }
    }
    __syncthreads();
    const int nsel = (cnt < TOPK) ? cnt : TOPK;

    if (tid < 64) {
        float w = (tid < nsel) ? selW[tid] : 0.f;
        #pragma unroll
        for (int off = 32; off; off >>= 1) w += __shfl_down(w, off);
        if (tid == 0) sSum = w;
    }
    __syncthreads();
    const float inv = 1.0f / sSum;

    if (tid < DM) {
        float a = 0.f;
        for (int j = 0; j < nsel; ++j)
            a += selW[j] * v[((size_t)b * SEQ + selIdx[j]) * DM + tid];
        out[((size_t)b * SEQ + t) * DM + tid] = a * inv;
    }
}

extern "C" void kernel_launch(void* const* d_in, const int* in_sizes, int n_in,
                              void* d_out, int out_size, void* d_ws, size_t ws_size,
                              hipStream_t stream) {
    const float* q = (const float*)d_in[0];
    const float* k = (const float*)d_in[1];
    const float* v = (const float*)d_in[2];
    float* out = (float*)d_out;

    float* rq = (float*)d_ws;
    float* rk = rq + (size_t)BATCH * SEQ * DM;
    const size_t ropeBytes = 2ull * BATCH * SEQ * DM * sizeof(float);

    const int total = BATCH * SEQ * (DM / 2);
    hipLaunchKernelGGL(rope_prep, dim3((total + 255) / 256), dim3(256), 0, stream,
                       q, k, rq, rk);

    long long Wb = (long long)ws_size - (long long)ropeBytes;
    int cr0[64], cm[64], nch = 0;
    bool ok = (Wb > 0);
    int r0 = 0;
    while (ok && r0 < SEQ) {
        int m = SEQ - r0;
        while (m >= 64) {
            long long bytes = (long long)BATCH * m * (((r0 + m + 63) / 64) * 64) * 4;
            if (bytes <= Wb) break;
            m -= 64;
        }
        if (m < 64 || nch >= 64) { ok = false; break; }
        cr0[nch] = r0; cm[nch] = m; ++nch;
        r0 += m;
    }

    if (!ok) {
        hipLaunchKernelGGL(topk_attn, dim3(BATCH * SEQ), dim3(256), 0, stream,
                           rq, rk, v, out);
        return;
    }

    float* lgbuf = rk + (size_t)BATCH * SEQ * DM;
    for (int c = 0; c < nch; ++c) {
        const int R0 = cr0[c], M = cm[c];
        const int stride = ((R0 + M + 63) / 64) * 64;
        dim3 g1((R0 + M + 63) / 64, M / 64, BATCH);
        hipLaunchKernelGGL(logits_gemm, g1, dim3(256), 0, stream,
                           rq, rk, lgbuf, R0, M, stride);
        dim3 g2((M + 3) / 4, BATCH);
        hipLaunchKernelGGL(select_out2, g2, dim3(256), 0, stream,
                           lgbuf, v, out, R0, M, stride);
    }
}

// Round 6
// 247.018 us; speedup vs baseline: 7.9871x; 1.2530x over previous
//
#include <hip/hip_runtime.h>
#include <math.h>

#define BATCH 4
#define SEQ   4096
#define DM    128
#define TOPK  64
#define SCALE 0.08838834764831845f   // 1/sqrt(128)
#define CAP   384                    // candidate buffer per row

typedef short bf16x8 __attribute__((ext_vector_type(8)));
typedef float f32x4  __attribute__((ext_vector_type(4)));

// ---- bf16 helpers (RNE) ----
__device__ __forceinline__ unsigned short f2bf(float x) {
    unsigned u = __float_as_uint(x);
    u += 0x7FFFu + ((u >> 16) & 1u);
    return (unsigned short)(u >> 16);
}
__device__ __forceinline__ float bf2f(unsigned short h) {
    return __uint_as_float(((unsigned)h) << 16);
}
__device__ __forceinline__ void split3(float x, unsigned short& h,
                                       unsigned short& md, unsigned short& l) {
    h = f2bf(x);
    float r1 = x - bf2f(h);
    md = f2bf(r1);
    float r2 = r1 - bf2f(md);
    l = f2bf(r2);
}

__device__ __forceinline__ unsigned fmap(float f) {
    unsigned u = __float_as_uint(f);
    return (u & 0x80000000u) ? ~u : (u | 0x80000000u);
}
__device__ __forceinline__ float finv(unsigned u) {
    return (u & 0x80000000u) ? __uint_as_float(u & 0x7FFFFFFFu) : __uint_as_float(~u);
}
__device__ __forceinline__ float wave_fmax(float v) {
    #pragma unroll
    for (int m = 32; m; m >>= 1) v = fmaxf(v, __shfl_xor(v, m));
    return v;
}
__device__ __forceinline__ float wave_fsum(float v) {
    #pragma unroll
    for (int m = 32; m; m >>= 1) v += __shfl_xor(v, m);
    return v;
}
__device__ __forceinline__ int wave_isum(int v) {
    #pragma unroll
    for (int m = 32; m; m >>= 1) v += __shfl_xor(v, m);
    return v;
}
__device__ __forceinline__ unsigned wave_umax(unsigned v) {
    #pragma unroll
    for (int m = 32; m; m >>= 1) { unsigned o = __shfl_xor(v, m); v = (o > v) ? o : v; }
    return v;
}

// ---------- RoPE + 3-way bf16 decomposition (main path) ----------
__global__ void rope_decomp(const float* __restrict__ q, const float* __restrict__ k,
                            unsigned short* __restrict__ qh, unsigned short* __restrict__ qm,
                            unsigned short* __restrict__ ql, unsigned short* __restrict__ kh,
                            unsigned short* __restrict__ km, unsigned short* __restrict__ kl) {
    int idx = blockIdx.x * blockDim.x + threadIdx.x;
    const int total = BATCH * SEQ * (DM / 2);
    if (idx >= total) return;
    int i   = idx & 63;
    int pos = (idx >> 6) & (SEQ - 1);
    int b   = idx >> 18;
    float dv  = powf(10000.0f, (float)(2 * i) / (float)DM);
    float ang = (float)pos / dv;
    float sn, cs;
    sincosf(ang, &sn, &cs);
    size_t base = ((size_t)b * SEQ + pos) * DM + 2 * i;
    float qe = q[base], qo = q[base + 1];
    float ke = k[base], ko = k[base + 1];
    float q0 = (qe * cs - qo * sn) * SCALE, q1 = (qe * sn + qo * cs) * SCALE;
    float k0 = ke * cs - ko * sn,          k1 = ke * sn + ko * cs;
    unsigned short h, m2, l;
    split3(q0, h, m2, l); qh[base] = h;     qm[base] = m2;     ql[base] = l;
    split3(q1, h, m2, l); qh[base + 1] = h; qm[base + 1] = m2; ql[base + 1] = l;
    split3(k0, h, m2, l); kh[base] = h;     km[base] = m2;     kl[base] = l;
    split3(k1, h, m2, l); kh[base + 1] = h; km[base + 1] = m2; kl[base + 1] = l;
}

// ---------- Phase A: logits via bf16 MFMA, 128x128 tile, 6-term split ----------
__launch_bounds__(256, 2)
__global__ void logits_mfma(const unsigned short* __restrict__ qh, const unsigned short* __restrict__ qm,
                            const unsigned short* __restrict__ ql, const unsigned short* __restrict__ kh,
                            const unsigned short* __restrict__ km, const unsigned short* __restrict__ kl,
                            float* __restrict__ lg, int r0, int m, int stride) {
    const int st = blockIdx.x, qt = blockIdx.y, b = blockIdx.z;
    const int Q0 = r0 + qt * 128, S0 = st * 128;
    if (S0 > Q0 + 127) return;                     // block fully above diagonal
    const int tid = threadIdx.x, lane = tid & 63, w = tid >> 6;
    const int wm = (w >> 1) * 64, wn = (w & 1) * 64;
    if (S0 + wn > Q0 + wm + 63) return;            // wave fully masked (no barriers used)

    const int rA = Q0 + wm + (lane & 15);
    const int rB = S0 + wn + (lane & 15);
    const int dc = (lane >> 4) * 8;

    f32x4 acc[4][4] = {};
    #pragma unroll
    for (int kk = 0; kk < 4; ++kk) {
        const int doff = kk * 32 + dc;
        bf16x8 Ah[4], Am[4], Al[4], Bh[4], Bm[4], Bl[4];
        #pragma unroll
        for (int i = 0; i < 4; ++i) {
            size_t qoff = ((size_t)b * SEQ + rA + i * 16) * DM + doff;
            Ah[i] = *(const bf16x8*)(qh + qoff);
            Am[i] = *(const bf16x8*)(qm + qoff);
            Al[i] = *(const bf16x8*)(ql + qoff);
            size_t koff = ((size_t)b * SEQ + rB + i * 16) * DM + doff;
            Bh[i] = *(const bf16x8*)(kh + koff);
            Bm[i] = *(const bf16x8*)(km + koff);
            Bl[i] = *(const bf16x8*)(kl + koff);
        }
        #pragma unroll
        for (int i = 0; i < 4; ++i)
            #pragma unroll
            for (int j = 0; j < 4; ++j) {
                f32x4 c = acc[i][j];
                c = __builtin_amdgcn_mfma_f32_16x16x32_bf16(Ah[i], Bh[j], c, 0, 0, 0);
                c = __builtin_amdgcn_mfma_f32_16x16x32_bf16(Ah[i], Bm[j], c, 0, 0, 0);
                c = __builtin_amdgcn_mfma_f32_16x16x32_bf16(Am[i], Bh[j], c, 0, 0, 0);
                c = __builtin_amdgcn_mfma_f32_16x16x32_bf16(Ah[i], Bl[j], c, 0, 0, 0);
                c = __builtin_amdgcn_mfma_f32_16x16x32_bf16(Al[i], Bh[j], c, 0, 0, 0);
                c = __builtin_amdgcn_mfma_f32_16x16x32_bf16(Am[i], Bm[j], c, 0, 0, 0);
                acc[i][j] = c;
            }
    }

    // C/D layout (m89-verified): col = lane&15, row = (lane>>4)*4 + reg
    const int colb = lane & 15, rowb = (lane >> 4) * 4;
    #pragma unroll
    for (int i = 0; i < 4; ++i) {
        #pragma unroll
        for (int r = 0; r < 4; ++r) {
            int qrow = Q0 + wm + i * 16 + rowb + r;
            size_t base = ((size_t)(b * m + (qrow - r0))) * stride;
            #pragma unroll
            for (int j = 0; j < 4; ++j) {
                int col = S0 + wn + j * 16 + colb;
                if (col <= qrow) lg[base + col] = acc[i][j][r];
            }
        }
    }
}

// ---------- Phase B: one WAVE per row; threshold prefilter + exact rank ----------
__launch_bounds__(256)
__global__ void select_out2(const float* __restrict__ lg, const float* __restrict__ v,
                            float* __restrict__ out, int r0, int m, int stride) {
    __shared__ unsigned long long bufK[4][CAP];   // (fmap(val)<<32) | (SEQ - idx)
    __shared__ float sW[4][TOPK];
    __shared__ int   sI[4][TOPK];
    __shared__ int   cnt[4];

    const int w = threadIdx.x >> 6, lane = threadIdx.x & 63;
    const int x = blockIdx.x * 4 + w, b = blockIdx.y;
    if (x >= m) return;
    const int t = r0 + x, n = t + 1;
    const float* row = lg + ((size_t)(b * m + x)) * stride;
    const float4* row4 = (const float4*)row;
    const int nv4 = n >> 2, rem = n & 3;

    if (n <= TOPK) {
        float val = (lane < n) ? row[lane] : -3.0e38f;
        float M = wave_fmax(val);
        float wgt = (lane < n) ? expf(val - M) : 0.f;
        float S = wave_fsum(wgt);
        sW[w][lane] = wgt;
        float inv = 1.f / S;
        float a0 = 0.f, a1 = 0.f;
        for (int j = 0; j < n; ++j) {
            float wj = sW[w][j];
            size_t base = ((size_t)b * SEQ + j) * DM;
            a0 += wj * v[base + lane];
            a1 += wj * v[base + 64 + lane];
        }
        size_t ob = ((size_t)b * SEQ + t) * DM;
        out[ob + lane] = a0 * inv;
        out[ob + 64 + lane] = a1 * inv;
        return;
    }

    float T;
    if (n <= 300) {
        T = -3.0e38f;
    } else {
        float p  = 128.f / (float)n;
        float tt = sqrtf(-2.f * logf(p));
        T = tt - (2.30753f + 0.27061f * tt) / (1.f + 0.99229f * tt + 0.04481f * tt * tt);
    }

    unsigned um = 0u;
    float Tlo = -3.3e38f, Thi = 3.3e38f;
    int C = 0;
    for (int it = 0; it < 24; ++it) {
        int c = 0;
        unsigned lm = 0u;
        for (int i = lane; i < nv4; i += 64) {
            float4 r4 = row4[i];
            c += (r4.x >= T) + (r4.y >= T) + (r4.z >= T) + (r4.w >= T);
            if (it == 0) {
                unsigned u0 = fmap(r4.x), u1 = fmap(r4.y), u2 = fmap(r4.z), u3 = fmap(r4.w);
                unsigned a = u0 > u1 ? u0 : u1, bb = u2 > u3 ? u2 : u3;
                a = a > bb ? a : bb;
                lm = a > lm ? a : lm;
            }
        }
        if (lane < rem) {
            float val = row[nv4 * 4 + lane];
            c += (val >= T);
            if (it == 0) { unsigned u = fmap(val); lm = u > lm ? u : lm; }
        }
        C = wave_isum(c);
        if (it == 0) um = wave_umax(lm);
        if (C >= TOPK && C <= CAP) break;
        if (C < TOPK) Thi = T; else Tlo = T;
        if (Tlo > -3.2e38f && Thi < 3.2e38f) T = 0.5f * (Tlo + Thi);
        else if (C < TOPK)                   T = T - 0.45f;
        else                                 T = T + 0.35f;
    }
    const float M = finv(um);

    if (lane == 0) cnt[w] = 0;
    for (int i = lane; i < nv4; i += 64) {
        float4 r4 = row4[i];
        int s = i << 2;
        if (r4.x >= T) { int p = atomicAdd(&cnt[w], 1); if (p < CAP) bufK[w][p] = ((unsigned long long)fmap(r4.x) << 32) | (unsigned)(SEQ - s); }
        if (r4.y >= T) { int p = atomicAdd(&cnt[w], 1); if (p < CAP) bufK[w][p] = ((unsigned long long)fmap(r4.y) << 32) | (unsigned)(SEQ - (s + 1)); }
        if (r4.z >= T) { int p = atomicAdd(&cnt[w], 1); if (p < CAP) bufK[w][p] = ((unsigned long long)fmap(r4.z) << 32) | (unsigned)(SEQ - (s + 2)); }
        if (r4.w >= T) { int p = atomicAdd(&cnt[w], 1); if (p < CAP) bufK[w][p] = ((unsigned long long)fmap(r4.w) << 32) | (unsigned)(SEQ - (s + 3)); }
    }
    if (lane < rem) {
        float val = row[nv4 * 4 + lane];
        if (val >= T) { int p = atomicAdd(&cnt[w], 1); if (p < CAP) bufK[w][p] = ((unsigned long long)fmap(val) << 32) | (unsigned)(SEQ - (nv4 * 4 + lane)); }
    }
    int Cw = cnt[w];
    if (Cw > CAP) Cw = CAP;

    for (int c0 = lane; c0 < Cw; c0 += 64) {
        unsigned long long kc = bufK[w][c0];
        int r = 0;
        for (int j = 0; j < Cw; ++j) r += (bufK[w][j] > kc);
        if (r < TOPK) {
            sW[w][r] = expf(finv((unsigned)(kc >> 32)) - M);
            sI[w][r] = SEQ - (int)(kc & 0xFFFFFFFFu);
        }
    }

    float S = wave_fsum(sW[w][lane]);
    float inv = 1.f / S;

    float a0 = 0.f, a1 = 0.f;
    #pragma unroll 4
    for (int j = 0; j < TOPK; ++j) {
        float wj = sW[w][j];
        int idx = sI[w][j];
        size_t base = ((size_t)b * SEQ + idx) * DM;
        a0 += wj * v[base + lane];
        a1 += wj * v[base + 64 + lane];
    }
    size_t ob = ((size_t)b * SEQ + t) * DM;
    out[ob + lane] = a0 * inv;
    out[ob + 64 + lane] = a1 * inv;
}

// ---------- fallback path (small ws): fp32 rope + round-2 kernel ----------
__global__ void rope_prep(const float* __restrict__ q, const float* __restrict__ k,
                          float* __restrict__ rq, float* __restrict__ rk) {
    int idx = blockIdx.x * blockDim.x + threadIdx.x;
    const int total = BATCH * SEQ * (DM / 2);
    if (idx >= total) return;
    int i   = idx & 63;
    int pos = (idx >> 6) & (SEQ - 1);
    int b   = idx >> 18;
    float dv  = powf(10000.0f, (float)(2 * i) / (float)DM);
    float ang = (float)pos / dv;
    float sn, cs;
    sincosf(ang, &sn, &cs);
    size_t base = ((size_t)b * SEQ + pos) * DM + 2 * i;
    float qe = q[base], qo = q[base + 1];
    float ke = k[base], ko = k[base + 1];
    rq[base]     = qe * cs - qo * sn;
    rq[base + 1] = qe * sn + qo * cs;
    rk[base]     = ke * cs - ko * sn;
    rk[base + 1] = ke * sn + ko * cs;
}

__launch_bounds__(256)
__global__ void topk_attn(const float* __restrict__ rq, const float* __restrict__ rk,
                          const float* __restrict__ v, float* __restrict__ out) {
    __shared__ unsigned umap[SEQ];
    __shared__ float    qs[DM];
    __shared__ int      selIdx[TOPK];
    __shared__ float    selW[TOPK];
    __shared__ int      cnt;
    __shared__ float    redf[4];
    __shared__ int      redi[4];
    __shared__ float    sMax, sSum;

    const int t   = blockIdx.x & (SEQ - 1);
    const int b   = blockIdx.x >> 12;
    const int tid = threadIdx.x;
    const int lane = tid & 63, wid = tid >> 6;
    const int n = t + 1;

    if (tid < DM) qs[tid] = rq[((size_t)b * SEQ + t) * DM + tid];
    if (tid == 0) cnt = 0;
    __syncthreads();

    float lmax = -INFINITY;
    for (int s = tid; s < n; s += 256) {
        const float4* kr = (const float4*)(rk + ((size_t)b * SEQ + s) * DM);
        const float4* qr = (const float4*)qs;
        float acc = 0.f;
        #pragma unroll
        for (int d = 0; d < DM / 4; ++d) {
            float4 kv = kr[d]; float4 qv = qr[d];
            acc += kv.x * qv.x + kv.y * qv.y + kv.z * qv.z + kv.w * qv.w;
        }
        float lgv = acc * SCALE;
        umap[s] = fmap(lgv);
        lmax = fmaxf(lmax, lgv);
    }
    #pragma unroll
    for (int off = 32; off; off >>= 1) lmax = fmaxf(lmax, __shfl_down(lmax, off));
    if (lane == 0) redf[wid] = lmax;
    __syncthreads();
    if (tid == 0) sMax = fmaxf(fmaxf(redf[0], redf[1]), fmaxf(redf[2], redf[3]));
    __syncthreads();
    const float M = sMax;

    const int K = (n < TOPK) ? n : TOPK;
    unsigned thr = 0u;
    if (n > TOPK) {
        unsigned long long lo = 0ull, hi = (unsigned long long)fmap(M);
        while (lo < hi) {
            unsigned long long mid = (lo + hi + 1ull) >> 1;
            unsigned m32 = (unsigned)mid;
            int c = 0;
            for (int s = tid; s < n; s += 256) c += (umap[s] >= m32) ? 1 : 0;
            #pragma unroll
            for (int off = 32; off; off >>= 1) c += __shfl_down(c, off);
            if (lane == 0) redi[wid] = c;
            __syncthreads();
            int tot = redi[0] + redi[1] + redi[2] + redi[3];
            __syncthreads();
            if (tot >= K) lo = mid; else hi = mid - 1ull;
        }
        thr = (unsigned)lo;
    }

    for (int s = tid; s < n; s += 256) {
        if (umap[s] > thr) {
            int p = atomicAdd(&cnt, 1);
            if (p < TOPK) { selIdx[p] = s; selW[p] = expf(finv(umap[s]) - M); }
        }
    }
    __syncthreads();
    for (int s = tid; s < n; s += 256) {
        if (umap[s] == thr) {
            int p = atomicAdd(&cnt, 1);
            if (p < TOPK) { selIdx[p] = s; selW[p] = expf(finv(umap[s]) - M); }
        }
    }
    __syncthreads();
    const int nsel = (cnt < TOPK) ? cnt : TOPK;

    if (tid < 64) {
        float w = (tid < nsel) ? selW[tid] : 0.f;
        #pragma unroll
        for (int off = 32; off; off >>= 1) w += __shfl_down(w, off);
        if (tid == 0) sSum = w;
    }
    __syncthreads();
    const float inv = 1.0f / sSum;

    if (tid < DM) {
        float a = 0.f;
        for (int j = 0; j < nsel; ++j)
            a += selW[j] * v[((size_t)b * SEQ + selIdx[j]) * DM + tid];
        out[((size_t)b * SEQ + t) * DM + tid] = a * inv;
    }
}

extern "C" void kernel_launch(void* const* d_in, const int* in_sizes, int n_in,
                              void* d_out, int out_size, void* d_ws, size_t ws_size,
                              hipStream_t stream) {
    const float* q = (const float*)d_in[0];
    const float* k = (const float*)d_in[1];
    const float* v = (const float*)d_in[2];
    float* out = (float*)d_out;

    const size_t plane = (size_t)BATCH * SEQ * DM;          // elements per plane
    const size_t planesBytes = 6 * plane * sizeof(unsigned short);   // ~25 MB

    // plan 128-granular query-row chunks for the fp32 logits buffer
    long long Wb = (long long)ws_size - (long long)planesBytes;
    int cr0[64], cm[64], nch = 0;
    bool ok = (Wb > 0);
    int r0 = 0;
    while (ok && r0 < SEQ) {
        int m = SEQ - r0;
        while (m >= 128) {
            long long stride = ((r0 + m + 127) / 128) * 128;
            long long bytes = (long long)BATCH * m * stride * 4;
            if (bytes <= Wb) break;
            m -= 128;
        }
        if (m < 128 || nch >= 64) { ok = false; break; }
        cr0[nch] = r0; cm[nch] = m; ++nch;
        r0 += m;
    }

    const int total = BATCH * SEQ * (DM / 2);

    if (!ok) {   // small-ws fallback: fp32 rope + round-2 kernel (needs 16 MB)
        float* rq = (float*)d_ws;
        float* rk = rq + plane;
        hipLaunchKernelGGL(rope_prep, dim3((total + 255) / 256), dim3(256), 0, stream,
                           q, k, rq, rk);
        hipLaunchKernelGGL(topk_attn, dim3(BATCH * SEQ), dim3(256), 0, stream,
                           rq, rk, v, out);
        return;
    }

    unsigned short* qh = (unsigned short*)d_ws;
    unsigned short* qm = qh + plane;
    unsigned short* ql = qm + plane;
    unsigned short* kh = ql + plane;
    unsigned short* km = kh + plane;
    unsigned short* kl = km + plane;
    float* lgbuf = (float*)((char*)d_ws + planesBytes);

    hipLaunchKernelGGL(rope_decomp, dim3((total + 255) / 256), dim3(256), 0, stream,
                       q, k, qh, qm, ql, kh, km, kl);

    for (int c = 0; c < nch; ++c) {
        const int R0 = cr0[c], M = cm[c];
        const int stride = ((R0 + M + 127) / 128) * 128;
        dim3 g1((R0 + M + 127) / 128, M / 128, BATCH);
        hipLaunchKernelGGL(logits_mfma, g1, dim3(256), 0, stream,
                           qh, qm, ql, kh, km, kl, lgbuf, R0, M, stride);
        dim3 g2((M + 3) / 4, BATCH);
        hipLaunchKernelGGL(select_out2, g2, dim3(256), 0, stream,
                           lgbuf, v, out, R0, M, stride);
    }
}